// Round 6
// baseline (1973.279 us; speedup 1.0000x reference)
//
#include <hip/hip_runtime.h>
#include <math.h>

#define T_STEPS 256
#define BATCH   256
#define DDIM    128
#define NH      10

// ---------- DPP helpers (VALU pipe) ----------
// update_dpp(old, src, dpp_ctrl, row_mask, bank_mask, bound_ctrl)
template<int CTRL, int RMASK, int BMASK>
__device__ __forceinline__ float dppz(float x){
  return __int_as_float(__builtin_amdgcn_update_dpp(
      0, __float_as_int(x), CTRL, RMASK, BMASK, true));
}

// quad_perm full-lane permute (verified R5)
template<int CTRL>
__device__ __forceinline__ float qperm(float x){
  int xi = __float_as_int(x);
  return __int_as_float(__builtin_amdgcn_update_dpp(xi, xi, CTRL, 0xF, 0xF, false));
}

// xor-4 / xor-8 within a 16-lane row via two bank-masked DPP movs.
// Direction convention (verified by R4's red63: row_shr accumulates toward
// lane 63): row_shr:N = dest n <- src n-N ; row_shl:N = dest n <- src n+N.
// xor-4: banks {0,2} (lanes 0-3, 8-11) need n+4 -> row_shl:4, bank_mask 0x5;
//        banks {1,3} need n-4 -> row_shr:4, bank_mask 0xA.   (R3 had these
//        bank masks SWAPPED - that was the R3 correctness bug.)
__device__ __forceinline__ float lane_xor4(float x){
  int xi = __float_as_int(x);
  int t = __builtin_amdgcn_update_dpp(xi, xi, 0x104, 0xF, 0x5, false); // row_shl:4
  t     = __builtin_amdgcn_update_dpp(t,  xi, 0x114, 0xF, 0xA, false); // row_shr:4
  return __int_as_float(t);
}
// xor-8: banks {0,1} need n+8 -> row_shl:8 mask 0x3; banks {2,3} -> row_shr:8 mask 0xC.
__device__ __forceinline__ float lane_xor8(float x){
  int xi = __float_as_int(x);
  int t = __builtin_amdgcn_update_dpp(xi, xi, 0x108, 0xF, 0x3, false); // row_shl:8
  t     = __builtin_amdgcn_update_dpp(t,  xi, 0x118, 0xF, 0xC, false); // row_shr:8
  return __int_as_float(t);
}

// Canonical wave64 ladder (verified R4): lane 63 ends with the full sum.
__device__ __forceinline__ float red63(float v){
  v += dppz<0x111, 0xF, 0xF>(v);   // row_shr:1
  v += dppz<0x112, 0xF, 0xF>(v);   // row_shr:2
  v += dppz<0x114, 0xF, 0xE>(v);   // row_shr:4  bank_mask:0xe
  v += dppz<0x118, 0xF, 0xC>(v);   // row_shr:8  bank_mask:0xc
  v += dppz<0x142, 0xA, 0xF>(v);   // row_bcast:15 row_mask:0xa
  v += dppz<0x143, 0xC, 0xF>(v);   // row_bcast:31 row_mask:0xc
  return v;
}
__device__ __forceinline__ float wave_sum_b(float v){
  return __int_as_float(__builtin_amdgcn_readlane(__float_as_int(red63(v)), 63));
}

// ---------- dual-sim RX primitives (two independent statevectors per wave) ----------
template<int BIT>
__device__ __forceinline__ void rx_reg2(float pcv, float psv,
                                        float* re0, float* im0, float* re1, float* im1){
  #pragma unroll
  for (int r = 0; r < 16; ++r){
    if (r & (1 << BIT)) continue;
    const int r1 = r | (1 << BIT);
    float a0, b0, a1, b1;
    a0 = re0[r]; b0 = im0[r]; a1 = re0[r1]; b1 = im0[r1];
    re0[r]  = fmaf(pcv, a0,  psv * b1);
    im0[r]  = fmaf(pcv, b0, -psv * a1);
    re0[r1] = fmaf(pcv, a1,  psv * b0);
    im0[r1] = fmaf(pcv, b1, -psv * a0);
    a0 = re1[r]; b0 = im1[r]; a1 = re1[r1]; b1 = im1[r1];
    re1[r]  = fmaf(pcv, a0,  psv * b1);
    im1[r]  = fmaf(pcv, b0, -psv * a1);
    re1[r1] = fmaf(pcv, a1,  psv * b0);
    im1[r1] = fmaf(pcv, b1, -psv * a0);
  }
}

// generic cross-lane RX stage; XF is a lane-exchange functor type tag via template fn ptr
#define RX_LANE2(FETCH)                                                        \
  { _Pragma("unroll")                                                          \
    for (int r = 0; r < 16; ++r){                                              \
      float oa0 = FETCH(re0[r]), ob0 = FETCH(im0[r]);                          \
      float oa1 = FETCH(re1[r]), ob1 = FETCH(im1[r]);                          \
      re0[r] = fmaf(pcv, re0[r],  psv * ob0);                                  \
      im0[r] = fmaf(pcv, im0[r], -psv * oa0);                                  \
      re1[r] = fmaf(pcv, re1[r],  psv * ob1);                                  \
      im1[r] = fmaf(pcv, im1[r], -psv * oa1);                                  \
    } }

__device__ __forceinline__ float shfl32(float x){ return __shfl_xor(x, 32, 64); }
__device__ __forceinline__ float shfl16(float x){ return __shfl_xor(x, 16, 64); }
__device__ __forceinline__ float qp2(float x){ return qperm<0x4E>(x); }  // xor-2
__device__ __forceinline__ float qp1(float x){ return qperm<0xB1>(x); }  // xor-1

// One RX(p) layer over all 10 wires for BOTH sims (gates commute; order free).
__device__ __forceinline__ void rx_layer2(const float* pc, const float* ps,
                                          float* re0, float* im0, float* re1, float* im1){
  { float pcv = pc[0], psv = ps[0]; RX_LANE2(shfl32) }    // wire0: xor-32 (ds)
  { float pcv = pc[1], psv = ps[1]; RX_LANE2(shfl16) }    // wire1: xor-16 (ds)
  { float pcv = pc[2], psv = ps[2]; RX_LANE2(lane_xor8) } // wire2: xor-8 (DPP)
  { float pcv = pc[3], psv = ps[3]; RX_LANE2(lane_xor4) } // wire3: xor-4 (DPP)
  { float pcv = pc[4], psv = ps[4]; RX_LANE2(qp2) }       // wire4: xor-2 (DPP)
  { float pcv = pc[5], psv = ps[5]; RX_LANE2(qp1) }       // wire5: xor-1 (DPP)
  rx_reg2<3>(pc[6], ps[6], re0, im0, re1, im1);
  rx_reg2<2>(pc[7], ps[7], re0, im0, re1, im1);
  rx_reg2<1>(pc[8], ps[8], re0, im0, re1, im1);
  rx_reg2<0>(pc[9], ps[9], re0, im0, re1, im1);
}

// Circuit algebra as in R2-R5:  dataRX(x); [RX(p); Cring] x2  ==
//   [build product state(x+p) at K j] ; RX(p) ; [measure with K^-1 parity masks].
// NEW in R6: 2 sims per wave (wave0: gates f,i; wave1: g,o) - two independent
// instruction streams per SIMD fill the latency stalls of 1-wave/SIMD execution.
__global__ void __launch_bounds__(128)
__attribute__((amdgpu_waves_per_eu(1, 1)))
qlstm_kernel(const float* __restrict__ inp, const float* __restrict__ rxp,
             const float* __restrict__ Wf, const float* __restrict__ bf,
             const float* __restrict__ Wi, const float* __restrict__ bi,
             const float* __restrict__ Wg, const float* __restrict__ bg,
             const float* __restrict__ Wo, const float* __restrict__ bo,
             float* __restrict__ out)
{
  const int b    = blockIdx.x;
  const int tid  = threadIdx.x;
  const int wid  = tid >> 6;     // wave id 0/1; sims = gates {2*wid, 2*wid+1}
  const int lane = tid & 63;

  __shared__ float gateV[2][4][64];  // [t&1][gate][lane-slot], padded; slots >=10 stay 0
  #pragma unroll
  for (int i = tid; i < 2*4*64; i += 128) ((float*)gateV)[i] = 0.f;

  const float* Wp[2]; const float* bp[2];
  if (wid == 0){ Wp[0] = Wf; bp[0] = bf; Wp[1] = Wi; bp[1] = bi; }
  else         { Wp[0] = Wg; bp[0] = bg; Wp[1] = Wo; bp[1] = bo; }

  float wA[2][NH], wB[2][NH], wC[2][NH], bT[2][NH];
  #pragma unroll
  for (int s = 0; s < 2; ++s)
    #pragma unroll
    for (int w = 0; w < NH; ++w){
      wA[s][w] = Wp[s][w*138 + lane];
      wB[s][w] = Wp[s][w*138 + 64 + lane];
      wC[s][w] = (lane < NH) ? Wp[s][w*138 + 128 + lane] : 0.f;
      bT[s][w] = bp[s][w] + rxp[w];
    }

  float pc[NH], ps[NH];
  #pragma unroll
  for (int w = 0; w < NH; ++w){
    float th = 0.5f * rxp[w];
    pc[w] = cosf(th);
    ps[w] = sinf(th);
  }

  // ---- hoisted lane-dependent constants ----
  const int l5 = (lane>>5)&1, l4 = (lane>>4)&1, l3 = (lane>>3)&1;
  const int l2 = (lane>>2)&1, l1 = (lane>>1)&1, l0 = lane&1;
  const int pb2 = l4^l3, pb3 = l3^l2, pb4 = l2^l1, pb5 = l1^l0;
  const int a0 = l5, a1 = l5^l4, a6 = l0;
  const int n2345 = pb2 + pb3 + pb4 + pb5;

  // phase (-i)^k per reg packed into two 16-bit masks (saves 32 VGPRs vs cre/cim)
  int oddmask = 0, negmask = 0;
  #pragma unroll
  for (int r = 0; r < 16; ++r){
    const int R0 = r&1, R1 = (r>>1)&1, R2 = (r>>2)&1, R3 = (r>>3)&1;
    const int b7 = R2^R3, b8 = R1^R2, b9 = R0^R1;
    int k = (n2345 + b7 + b8 + b9 + (a0^R0) + (a1^R0) + (a6^R3)) & 3;
    if (k & 1) oddmask |= (1 << r);               // k odd -> amplitude is imaginary
    if (k == 1 || k == 2) negmask |= (1 << r);    // sign: k=1 -> -i, k=2 -> -1
  }

  const float ls0 = (__popc(lane & 0x1F) & 1) ? -1.f : 1.f;
  const float ls1 = (__popc(lane & 0x30) & 1) ? -1.f : 1.f;
  const float ls2 = (__popc(lane & 0x38) & 1) ? -1.f : 1.f;
  const float ls3 = (__popc(lane & 0x3C) & 1) ? -1.f : 1.f;
  const float ls4 = (__popc(lane & 0x3E) & 1) ? -1.f : 1.f;
  const float ls5 = (__popc(lane & 0x3F) & 1) ? -1.f : 1.f;

  float h = 0.f, cc = 0.f;   // lane j's h_j, c_j (redundant in both waves; j>=10 stays 0)

  const float* x0 = inp + (size_t)b * DDIM;
  float xa = x0[lane];
  float xb = x0[64 + lane];

  __syncthreads();

  #pragma unroll 1
  for (int t = 0; t < T_STEPS; ++t){
    float xaC = xa, xbC = xb;
    if (t + 1 < T_STEPS){
      const float* nx = inp + ((size_t)(t+1) * BATCH + b) * DDIM;
      xa = nx[lane];
      xb = nx[64 + lane];
    }

    // ---- gate pre-activation half-angles for both sims ----
    float cs[2][NH], sn[2][NH];
    #pragma unroll
    for (int w = 0; w < NH; ++w){
      float p0 = fmaf(xaC, wA[0][w], fmaf(xbC, wB[0][w], h * wC[0][w]));
      float p1 = fmaf(xaC, wA[1][w], fmaf(xbC, wB[1][w], h * wC[1][w]));
      float t0 = 0.5f * (bT[0][w] + wave_sum_b(p0));
      float t1 = 0.5f * (bT[1][w] + wave_sum_b(p1));
      cs[0][w] = __cosf(t0);  sn[0][w] = __sinf(t0);
      cs[1][w] = __cosf(t1);  sn[1][w] = __sinf(t1);
    }

    // ---- build both statevectors: u[j] = prod-state(x+p) at K j, phase (-i)^k ----
    float re[2][16], im[2][16];
    #pragma unroll
    for (int s = 0; s < 2; ++s){
      float f2 = pb2 ? sn[s][2] : cs[s][2];
      float f3 = pb3 ? sn[s][3] : cs[s][3];
      float f4 = pb4 ? sn[s][4] : cs[s][4];
      float f5 = pb5 ? sn[s][5] : cs[s][5];
      float m2345 = (f2*f3)*(f4*f5);

      float q0 = (a0 ? sn[s][0] : cs[s][0]) * (a1 ? sn[s][1] : cs[s][1]);
      float q1 = (a0 ? cs[s][0] : sn[s][0]) * (a1 ? cs[s][1] : sn[s][1]);
      float v0 = a6 ? sn[s][6] : cs[s][6];
      float v1 = a6 ? cs[s][6] : sn[s][6];
      float mq0 = m2345 * q0, mq1 = m2345 * q1;
      float Z00 = mq0*v0, Z01 = mq0*v1, Z10 = mq1*v0, Z11 = mq1*v1;

      float A00 = cs[s][7]*cs[s][8], A01 = cs[s][7]*sn[s][8];
      float A10 = sn[s][7]*cs[s][8], A11 = sn[s][7]*sn[s][8];

      #pragma unroll
      for (int r = 0; r < 16; ++r){
        const int R0 = r&1, R3 = (r>>3)&1, R1 = (r>>1)&1, R2 = (r>>2)&1;
        const int b7 = R2^R3, b8 = R1^R2, b9 = R0^R1;
        float A  = (b7 ? (b8 ? A11 : A10) : (b8 ? A01 : A00));
        float P  = A * (b9 ? sn[s][9] : cs[s][9]);
        float Zc = R0 ? (R3 ? Z11 : Z10) : (R3 ? Z01 : Z00);
        float m  = P * Zc;
        float sgn = (negmask & (1 << r)) ? -m : m;
        bool  od  = (oddmask & (1 << r)) != 0;
        re[s][r] = od ? 0.f : sgn;
        im[s][r] = od ? sgn : 0.f;
      }
    }

    // ---- RX(p) layer on both sims (interleaved; CNOT rings folded out) ----
    rx_layer2(pc, ps, re[0], im[0], re[1], im[1]);

    // ---- PauliZ expectations (K^-1 parity masks); totals in lane 63 ----
    float e[2][NH];
    #pragma unroll
    for (int s = 0; s < 2; ++s){
      float tot = 0.f, q8 = 0.f, qC = 0.f, qE = 0.f, qF = 0.f;
      #pragma unroll
      for (int r = 0; r < 16; ++r){
        float p = fmaf(re[s][r], re[s][r], im[s][r]*im[s][r]);
        tot += p;
        q8 += ((__popc(r & 0x8) & 1) ? -p : p);
        qC += ((__popc(r & 0xC) & 1) ? -p : p);
        qE += ((__popc(r & 0xE) & 1) ? -p : p);
        qF += ((__popc(r & 0xF) & 1) ? -p : p);
      }
      e[s][0] = red63(ls0 * qF);
      e[s][1] = red63(ls1 * tot);
      e[s][2] = red63(ls2 * tot);
      e[s][3] = red63(ls3 * tot);
      e[s][4] = red63(ls4 * tot);
      e[s][5] = red63(ls5 * tot);
      e[s][6] = red63(ls5 * q8);
      e[s][7] = red63(ls5 * qC);
      e[s][8] = red63(ls5 * qE);
      e[s][9] = red63(ls5 * qF);
    }

    // ---- activation (gate 2 = g-gate = tanh; others sigmoid). Wave-uniform. ----
    float act[2][NH];
    #pragma unroll
    for (int s = 0; s < 2; ++s){
      bool is_tanh = (wid == 1) && (s == 0);   // gate index 2
      #pragma unroll
      for (int w = 0; w < NH; ++w){
        float z = is_tanh ? 2.f * e[s][w] : e[s][w];
        float u = 1.f / (1.f + __expf(-z));
        act[s][w] = is_tanh ? fmaf(2.f, u, -1.f) : u;
      }
    }
    if (lane == 63){
      #pragma unroll
      for (int s = 0; s < 2; ++s)
        #pragma unroll
        for (int w = 0; w < NH; ++w) gateV[t & 1][2*wid + s][w] = act[s][w];
    }
    __syncthreads();

    // ---- per-lane redundant cell update ----
    float fv = gateV[t & 1][0][lane];
    float iv = gateV[t & 1][1][lane];
    float gv = gateV[t & 1][2][lane];
    float ov = gateV[t & 1][3][lane];
    cc = fmaf(fv, cc, iv * gv);
    float e2c = __expf(2.f * cc);
    h = ov * ((e2c - 1.f) / (e2c + 1.f));

    if (wid == 0 && lane < NH)
      out[((size_t)t * BATCH + b) * NH + lane] = h;
  }

  // hT, cT
  if (wid == 0 && lane < NH){
    const size_t ysN = (size_t)T_STEPS * BATCH * NH;
    out[ysN + (size_t)b * NH + lane]                      = h;
    out[ysN + (size_t)BATCH * NH + (size_t)b * NH + lane] = cc;
  }
}

extern "C" void kernel_launch(void* const* d_in, const int* in_sizes, int n_in,
                              void* d_out, int out_size, void* d_ws, size_t ws_size,
                              hipStream_t stream)
{
  qlstm_kernel<<<BATCH, 128, 0, stream>>>(
      (const float*)d_in[0], (const float*)d_in[1],
      (const float*)d_in[2], (const float*)d_in[3],
      (const float*)d_in[4], (const float*)d_in[5],
      (const float*)d_in[6], (const float*)d_in[7],
      (const float*)d_in[8], (const float*)d_in[9],
      (float*)d_out);
}

// Round 7
// 1163.583 us; speedup vs baseline: 1.6959x; 1.6959x over previous
//
#include <hip/hip_runtime.h>
#include <math.h>

#define T_STEPS 256
#define BATCH   256
#define DDIM    128
#define NH      10

// ---------- DPP helpers (VALU pipe) ----------
// update_dpp(old, src, dpp_ctrl, row_mask, bank_mask, bound_ctrl)
template<int CTRL, int RMASK, int BMASK>
__device__ __forceinline__ float dppz(float x){
  return __int_as_float(__builtin_amdgcn_update_dpp(
      0, __float_as_int(x), CTRL, RMASK, BMASK, true));
}

// quad_perm full-lane permute (verified R5/R6)
template<int CTRL>
__device__ __forceinline__ float qperm(float x){
  int xi = __float_as_int(x);
  return __int_as_float(__builtin_amdgcn_update_dpp(xi, xi, CTRL, 0xF, 0xF, false));
}

// xor-4 / xor-8 within a 16-lane row via two bank-masked DPP movs.
// Convention (verified by red63 direction + R6 end-to-end pass):
// row_shr:N = dest n <- src n-N ; row_shl:N = dest n <- src n+N.
__device__ __forceinline__ float lane_xor4(float x){
  int xi = __float_as_int(x);
  int t = __builtin_amdgcn_update_dpp(xi, xi, 0x104, 0xF, 0x5, false); // row_shl:4, banks {0,2}
  t     = __builtin_amdgcn_update_dpp(t,  xi, 0x114, 0xF, 0xA, false); // row_shr:4, banks {1,3}
  return __int_as_float(t);
}
__device__ __forceinline__ float lane_xor8(float x){
  int xi = __float_as_int(x);
  int t = __builtin_amdgcn_update_dpp(xi, xi, 0x108, 0xF, 0x3, false); // row_shl:8, banks {0,1}
  t     = __builtin_amdgcn_update_dpp(t,  xi, 0x118, 0xF, 0xC, false); // row_shr:8, banks {2,3}
  return __int_as_float(t);
}

// Canonical wave64 ladder (verified R4+): lane 63 ends with the full sum.
__device__ __forceinline__ float red63(float v){
  v += dppz<0x111, 0xF, 0xF>(v);   // row_shr:1
  v += dppz<0x112, 0xF, 0xF>(v);   // row_shr:2
  v += dppz<0x114, 0xF, 0xE>(v);   // row_shr:4  bank_mask:0xe
  v += dppz<0x118, 0xF, 0xC>(v);   // row_shr:8  bank_mask:0xc
  v += dppz<0x142, 0xA, 0xF>(v);   // row_bcast:15 row_mask:0xa
  v += dppz<0x143, 0xC, 0xF>(v);   // row_bcast:31 row_mask:0xc
  return v;
}
__device__ __forceinline__ float wave_sum_b(float v){
  return __int_as_float(__builtin_amdgcn_readlane(__float_as_int(red63(v)), 63));
}

// RX on a reg-bit wire (bit BIT of the 4 low index bits). Pure VALU.
template<int BIT>
__device__ __forceinline__ void rx_reg(float c, float s, float* re, float* im){
  #pragma unroll
  for (int r = 0; r < 16; ++r){
    if (r & (1 << BIT)) continue;
    const int r1 = r | (1 << BIT);
    float a0 = re[r], b0 = im[r], a1 = re[r1], b1 = im[r1];
    re[r]  = fmaf(c, a0,  s * b1);
    im[r]  = fmaf(c, b0, -s * a1);
    re[r1] = fmaf(c, a1,  s * b0);
    im[r1] = fmaf(c, b1, -s * a0);
  }
}

// RX on a lane-bit wire via __shfl_xor (ds pipe; masks 32, 16 only):
__device__ __forceinline__ void rx_lane(float c, float s, int mask, float* re, float* im){
  #pragma unroll
  for (int r = 0; r < 16; ++r){
    float oa = __shfl_xor(re[r], mask, 64);
    float ob = __shfl_xor(im[r], mask, 64);
    re[r] = fmaf(c, re[r],  s * ob);
    im[r] = fmaf(c, im[r], -s * oa);
  }
}

// RX on a lane-bit wire via a DPP exchange functor
#define RX_LANE_DPP(FETCH, cv, sv)                                             \
  { _Pragma("unroll")                                                          \
    for (int r = 0; r < 16; ++r){                                              \
      float oa = FETCH(re[r]);                                                 \
      float ob = FETCH(im[r]);                                                 \
      re[r] = fmaf(cv, re[r],  sv * ob);                                       \
      im[r] = fmaf(cv, im[r], -sv * oa);                                       \
    } }

__device__ __forceinline__ float qp2(float x){ return qperm<0x4E>(x); }  // xor-2
__device__ __forceinline__ float qp1(float x){ return qperm<0xB1>(x); }  // xor-1

// One RX layer over all 10 wires. Wire w <-> index bit 9-w. Gate order free (commuting).
// ds stages (masks 32,16) first, then DPP stages (8,4,2,1), then reg wires.
__device__ __forceinline__ void rx_layer(const float* c, const float* s, float* re, float* im){
  rx_lane(c[0], s[0], 32, re, im);           // xor-32 (ds)
  rx_lane(c[1], s[1], 16, re, im);           // xor-16 (ds)
  RX_LANE_DPP(lane_xor8, c[2], s[2])         // xor-8 (DPP, proven R6)
  RX_LANE_DPP(lane_xor4, c[3], s[3])         // xor-4 (DPP, proven R6)
  RX_LANE_DPP(qp2,       c[4], s[4])         // xor-2 (DPP, proven R5)
  RX_LANE_DPP(qp1,       c[5], s[5])         // xor-1 (DPP, proven R5)
  rx_reg<3>(c[6], s[6], re, im);
  rx_reg<2>(c[7], s[7], re, im);
  rx_reg<1>(c[8], s[8], re, im);
  rx_reg<0>(c[9], s[9], re, im);
}

// Circuit algebra (K = composite CNOT-ring index map, s_out[i] = s_in[K i]):
//   dataRX(x); [RX(p); C] x2  ==  [build product state at K j] ; RX(p) ; [measure
//   with row_w(K^-1) parity masks].  R6 lesson: keep 4 waves/block, 1 sim/wave
//   (2-sims/wave ILP packing at 2 waves/CU regressed 1.58x).
__global__ void __launch_bounds__(256)
__attribute__((amdgpu_waves_per_eu(1, 1)))
qlstm_kernel(const float* __restrict__ inp, const float* __restrict__ rxp,
             const float* __restrict__ Wf, const float* __restrict__ bf,
             const float* __restrict__ Wi, const float* __restrict__ bi,
             const float* __restrict__ Wg, const float* __restrict__ bg,
             const float* __restrict__ Wo, const float* __restrict__ bo,
             float* __restrict__ out)
{
  const int b    = blockIdx.x;
  const int tid  = threadIdx.x;
  const int g    = tid >> 6;     // gate index, wave-uniform
  const int lane = tid & 63;

  __shared__ float gateV[2][4][64];  // double-buffered; padded to 64 lanes
  #pragma unroll
  for (int i = tid; i < 2*4*64; i += 256) ((float*)gateV)[i] = 0.f;

  const float* Wp = (g == 0) ? Wf : (g == 1) ? Wi : (g == 2) ? Wg : Wo;
  const float* bp = (g == 0) ? bf : (g == 1) ? bi : (g == 2) ? bg : bo;

  // Per-lane weight slices; bias folded with rx param (layer-1 RX merge).
  float wA[NH], wB[NH], wC[NH], bT[NH];
  #pragma unroll
  for (int w = 0; w < NH; ++w){
    wA[w] = Wp[w*138 + lane];
    wB[w] = Wp[w*138 + 64 + lane];
    wC[w] = (lane < NH) ? Wp[w*138 + 128 + lane] : 0.f;
    bT[w] = bp[w] + rxp[w];
  }

  // Layer-2 RX params (precise one-time trig).
  float pc[NH], ps[NH];
  #pragma unroll
  for (int w = 0; w < NH; ++w){
    float th = 0.5f * rxp[w];
    pc[w] = cosf(th);
    ps[w] = sinf(th);
  }

  // ---- hoisted lane-dependent constants ----
  const int l5 = (lane>>5)&1, l4 = (lane>>4)&1, l3 = (lane>>3)&1;
  const int l2 = (lane>>2)&1, l1 = (lane>>1)&1, l0 = lane&1;
  const int pb2 = l4^l3, pb3 = l3^l2, pb4 = l2^l1, pb5 = l1^l0;  // build selects, wires 2..5
  const int a0 = l5, a1 = l5^l4, a6 = l0;                         // mixed-wire lane parts
  const int n2345 = pb2 + pb3 + pb4 + pb5;

  // phase constants (-i)^k per reg (step-invariant)
  float cre[16], cim[16];
  #pragma unroll
  for (int r = 0; r < 16; ++r){
    const int R0 = r&1, R1 = (r>>1)&1, R2 = (r>>2)&1, R3 = (r>>3)&1;
    const int b7 = R2^R3, b8 = R1^R2, b9 = R0^R1;
    int k = (n2345 + b7 + b8 + b9 + (a0^R0) + (a1^R0) + (a6^R3)) & 3;
    cre[r] = (k==0) ? 1.f : (k==2) ? -1.f : 0.f;
    cim[r] = (k==1) ? -1.f : (k==3) ? 1.f : 0.f;
  }

  // measurement lane signs
  const float ls0 = (__popc(lane & 0x1F) & 1) ? -1.f : 1.f;
  const float ls1 = (__popc(lane & 0x30) & 1) ? -1.f : 1.f;
  const float ls2 = (__popc(lane & 0x38) & 1) ? -1.f : 1.f;
  const float ls3 = (__popc(lane & 0x3C) & 1) ? -1.f : 1.f;
  const float ls4 = (__popc(lane & 0x3E) & 1) ? -1.f : 1.f;
  const float ls5 = (__popc(lane & 0x3F) & 1) ? -1.f : 1.f;  // shared by w5..w9

  float h = 0.f, c = 0.f;   // per-lane cell state (lane j holds h_j, c_j; j>=10 stays 0)

  // prefetch t=0
  const float* x0 = inp + (size_t)b * DDIM;
  float xa = x0[lane];
  float xb = x0[64 + lane];

  __syncthreads();

  #pragma unroll 1
  for (int t = 0; t < T_STEPS; ++t){
    float xaC = xa, xbC = xb;
    if (t + 1 < T_STEPS){
      const float* nx = inp + ((size_t)(t+1) * BATCH + b) * DDIM;
      xa = nx[lane];
      xb = nx[64 + lane];
    }

    // ---- gate pre-activation angles (half-angles, bias+param folded) ----
    float cs[NH], sn[NH];
    #pragma unroll
    for (int w = 0; w < NH; ++w){
      float p  = fmaf(xaC, wA[w], fmaf(xbC, wB[w], h * wC[w]));
      float th = 0.5f * (bT[w] + wave_sum_b(p));
      cs[w] = __cosf(th);
      sn[w] = __sinf(th);
    }

    // ---- build u[j] = (product state with angles x+p) evaluated at K j ----
    float f2 = pb2 ? sn[2] : cs[2];
    float f3 = pb3 ? sn[3] : cs[3];
    float f4 = pb4 ? sn[4] : cs[4];
    float f5 = pb5 ? sn[5] : cs[5];
    float m2345 = (f2*f3)*(f4*f5);

    float q0 = (a0 ? sn[0] : cs[0]) * (a1 ? sn[1] : cs[1]);
    float q1 = (a0 ? cs[0] : sn[0]) * (a1 ? cs[1] : sn[1]);
    float v0 = a6 ? sn[6] : cs[6];
    float v1 = a6 ? cs[6] : sn[6];
    float mq0 = m2345 * q0, mq1 = m2345 * q1;
    float Z00 = mq0*v0, Z01 = mq0*v1, Z10 = mq1*v0, Z11 = mq1*v1;

    float A00 = cs[7]*cs[8], A01 = cs[7]*sn[8], A10 = sn[7]*cs[8], A11 = sn[7]*sn[8];

    float re[16], im[16];
    #pragma unroll
    for (int r = 0; r < 16; ++r){
      const int R0 = r&1, R1 = (r>>1)&1, R2 = (r>>2)&1, R3 = (r>>3)&1;
      const int b7 = R2^R3, b8 = R1^R2, b9 = R0^R1;
      float A  = (b7 ? (b8 ? A11 : A10) : (b8 ? A01 : A00));
      float P  = A * (b9 ? sn[9] : cs[9]);
      float Zc = R0 ? (R3 ? Z11 : Z10) : (R3 ? Z01 : Z00);
      float m  = P * Zc;
      re[r] = m * cre[r];
      im[r] = m * cim[r];
    }

    // ---- layer-2 RX (simple masks; CNOT rings folded out) ----
    rx_layer(pc, ps, re, im);

    // ---- PauliZ expectations with K^-1 parity masks; totals land in lane 63 ----
    float tot = 0.f, q8 = 0.f, qC = 0.f, qE = 0.f, qF = 0.f;
    #pragma unroll
    for (int r = 0; r < 16; ++r){
      float p = fmaf(re[r], re[r], im[r]*im[r]);
      tot += p;
      q8 += ((__popc(r & 0x8) & 1) ? -p : p);
      qC += ((__popc(r & 0xC) & 1) ? -p : p);
      qE += ((__popc(r & 0xE) & 1) ? -p : p);
      qF += ((__popc(r & 0xF) & 1) ? -p : p);
    }
    float e[NH];
    e[0] = red63(ls0 * qF);
    e[1] = red63(ls1 * tot);
    e[2] = red63(ls2 * tot);
    e[3] = red63(ls3 * tot);
    e[4] = red63(ls4 * tot);
    e[5] = red63(ls5 * tot);
    e[6] = red63(ls5 * q8);
    e[7] = red63(ls5 * qC);
    e[8] = red63(ls5 * qE);
    e[9] = red63(ls5 * qF);

    // ---- activation; only lane 63's values are meaningful/stored ----
    float act[NH];
    if (g == 2){
      #pragma unroll
      for (int w = 0; w < NH; ++w){
        float e2 = __expf(2.f * e[w]);
        act[w] = (e2 - 1.f) / (e2 + 1.f);
      }
    } else {
      #pragma unroll
      for (int w = 0; w < NH; ++w){
        act[w] = 1.f / (1.f + __expf(-e[w]));
      }
    }
    if (lane == 63){
      #pragma unroll
      for (int w = 0; w < NH; ++w) gateV[t & 1][g][w] = act[w];
    }
    __syncthreads();

    // ---- per-lane redundant cell update (h_j, c_j in lane j's registers) ----
    float fv = gateV[t & 1][0][lane];
    float iv = gateV[t & 1][1][lane];
    float gv = gateV[t & 1][2][lane];
    float ov = gateV[t & 1][3][lane];
    c = fmaf(fv, c, iv * gv);
    float e2c = __expf(2.f * c);
    h = ov * ((e2c - 1.f) / (e2c + 1.f));

    if (g == 0 && lane < NH)
      out[((size_t)t * BATCH + b) * NH + lane] = h;
  }

  // hT, cT
  if (g == 0 && lane < NH){
    const size_t ysN = (size_t)T_STEPS * BATCH * NH;
    out[ysN + (size_t)b * NH + lane]                      = h;
    out[ysN + (size_t)BATCH * NH + (size_t)b * NH + lane] = c;
  }
}

extern "C" void kernel_launch(void* const* d_in, const int* in_sizes, int n_in,
                              void* d_out, int out_size, void* d_ws, size_t ws_size,
                              hipStream_t stream)
{
  qlstm_kernel<<<BATCH, 256, 0, stream>>>(
      (const float*)d_in[0], (const float*)d_in[1],
      (const float*)d_in[2], (const float*)d_in[3],
      (const float*)d_in[4], (const float*)d_in[5],
      (const float*)d_in[6], (const float*)d_in[7],
      (const float*)d_in[8], (const float*)d_in[9],
      (float*)d_out);
}

// Round 8
// 1012.794 us; speedup vs baseline: 1.9484x; 1.1489x over previous
//
#include <hip/hip_runtime.h>
#include <math.h>

#define T_STEPS 256
#define BATCH   256
#define DDIM    128
#define NH      10

// ---------- DPP helpers (VALU pipe) ----------
template<int CTRL, int RMASK, int BMASK>
__device__ __forceinline__ float dppz(float x){
  return __int_as_float(__builtin_amdgcn_update_dpp(
      0, __float_as_int(x), CTRL, RMASK, BMASK, true));
}
template<int CTRL>
__device__ __forceinline__ float qperm(float x){
  int xi = __float_as_int(x);
  return __int_as_float(__builtin_amdgcn_update_dpp(xi, xi, CTRL, 0xF, 0xF, false));
}
// xor-4 / xor-8 within a 16-lane row (proven R6/R7).
__device__ __forceinline__ float lane_xor4(float x){
  int xi = __float_as_int(x);
  int t = __builtin_amdgcn_update_dpp(xi, xi, 0x104, 0xF, 0x5, false); // row_shl:4, banks {0,2}
  t     = __builtin_amdgcn_update_dpp(t,  xi, 0x114, 0xF, 0xA, false); // row_shr:4, banks {1,3}
  return __int_as_float(t);
}
__device__ __forceinline__ float lane_xor8(float x){
  int xi = __float_as_int(x);
  int t = __builtin_amdgcn_update_dpp(xi, xi, 0x108, 0xF, 0x3, false); // row_shl:8, banks {0,1}
  t     = __builtin_amdgcn_update_dpp(t,  xi, 0x118, 0xF, 0xC, false); // row_shr:8, banks {2,3}
  return __int_as_float(t);
}
// Canonical wave64 ladder (proven R4+): lane 63 ends with the full sum.
__device__ __forceinline__ float red63(float v){
  v += dppz<0x111, 0xF, 0xF>(v);
  v += dppz<0x112, 0xF, 0xF>(v);
  v += dppz<0x114, 0xF, 0xE>(v);
  v += dppz<0x118, 0xF, 0xC>(v);
  v += dppz<0x142, 0xA, 0xF>(v);
  v += dppz<0x143, 0xC, 0xF>(v);
  return v;
}
__device__ __forceinline__ float wave_sum_b(float v){
  return __int_as_float(__builtin_amdgcn_readlane(__float_as_int(red63(v)), 63));
}

#define NREG 8   // 8 complex amps per lane per wave (half statevector)

// RX on a reg-bit wire (bit BIT of the 3 reg bits). Pure VALU.
template<int BIT>
__device__ __forceinline__ void rx_reg(float c, float s, float* re, float* im){
  #pragma unroll
  for (int r = 0; r < NREG; ++r){
    if (r & (1 << BIT)) continue;
    const int r1 = r | (1 << BIT);
    float a0 = re[r], b0 = im[r], a1 = re[r1], b1 = im[r1];
    re[r]  = fmaf(c, a0,  s * b1);
    im[r]  = fmaf(c, b0, -s * a1);
    re[r1] = fmaf(c, a1,  s * b0);
    im[r1] = fmaf(c, b1, -s * a0);
  }
}
// RX on a lane-bit wire via __shfl_xor (ds pipe; masks 32, 16 only):
__device__ __forceinline__ void rx_lane(float c, float s, int mask, float* re, float* im){
  #pragma unroll
  for (int r = 0; r < NREG; ++r){
    float oa = __shfl_xor(re[r], mask, 64);
    float ob = __shfl_xor(im[r], mask, 64);
    re[r] = fmaf(c, re[r],  s * ob);
    im[r] = fmaf(c, im[r], -s * oa);
  }
}
#define RX_LANE_DPP(FETCH, cv, sv)                                             \
  { _Pragma("unroll")                                                          \
    for (int r = 0; r < NREG; ++r){                                            \
      float oa = FETCH(re[r]);                                                 \
      float ob = FETCH(im[r]);                                                 \
      re[r] = fmaf(cv, re[r],  sv * ob);                                       \
      im[r] = fmaf(cv, im[r], -sv * oa);                                       \
    } }
__device__ __forceinline__ float qp2(float x){ return qperm<0x4E>(x); }
__device__ __forceinline__ float qp1(float x){ return qperm<0xB1>(x); }

// ================= R8 layout =================
// Each gate-sim (1024 amps) is split across a WAVE PAIR: 512 amps/wave =
// 64 lanes x 8 regs. Index bits: wires 0..5 -> lane bits 5..0 (masks 32..1),
// wire 6 -> WAVE bit (cross-wave LDS exchange), wires 7,8,9 -> reg bits 2,1,0.
// Wire-space circuit algebra (verified R1-R7): build product-state(x+p) at
// K j ; RX(p) all 10 wires ; measure with K^-1 parity sets
//   S_0 = {1..9}, S_w = {0..w} (w>=1).
// K rows in wire space: beta_w = w_bit ^ pred_bit (+ w9 for beta0/beta1).
// New-coord betas: b0=L5^R0 b1=L5^L4^R0 b2=L4^L3 b3=L3^L2 b4=L2^L1 b5=L1^L0
//                  b6=L0^W  b7=W^R2  b8=R2^R1  b9=R1^R0
// Measurement masks: S0: lane 0x1F + W + reg 0x7 | S1..S5: lane 0x30..0x3F |
//   S6: lane 0x3F + W | S7: +reg 0x4 | S8: +reg 0x6 | S9: +reg 0x7.
// Wave sign sigma_w = -1 for w in {0,6,7,8,9} applied at partial combine.
__global__ void __launch_bounds__(512)
__attribute__((amdgpu_waves_per_eu(2)))
qlstm_kernel(const float* __restrict__ inp, const float* __restrict__ rxp,
             const float* __restrict__ Wf, const float* __restrict__ bf,
             const float* __restrict__ Wi, const float* __restrict__ bi,
             const float* __restrict__ Wg, const float* __restrict__ bg,
             const float* __restrict__ Wo, const float* __restrict__ bo,
             float* __restrict__ out)
{
  const int b    = blockIdx.x;
  const int tid  = threadIdx.x;
  const int wv   = tid >> 6;        // 0..7
  const int g    = wv >> 1;         // gate 0..3 (f,i,g,o)
  const int half = wv & 1;          // statevector half (wire-6 / wave bit)
  const int lane = tid & 63;

  // wire-6 exchange buffer: [gate][half][chunk][lane], chunk = re01,re23,im01,im23
  __shared__ float4 Sx[4][2][4][64];
  // measurement partials: [gate][half][slot]; slots 10..63 stay 0 forever
  __shared__ float part[4][2][64];
  ((float*)part)[tid] = 0.f;        // 4*2*64 = 512 = blockDim

  const float* Wp = (g == 0) ? Wf : (g == 1) ? Wi : (g == 2) ? Wg : Wo;
  const float* bp = (g == 0) ? bf : (g == 1) ? bi : (g == 2) ? bg : bo;

  float wA[NH], wB[NH], wC[NH], bT[NH];
  #pragma unroll
  for (int w = 0; w < NH; ++w){
    wA[w] = Wp[w*138 + lane];
    wB[w] = Wp[w*138 + 64 + lane];
    wC[w] = (lane < NH) ? Wp[w*138 + 128 + lane] : 0.f;
    bT[w] = bp[w] + rxp[w];
  }
  float pc[NH], ps[NH];
  #pragma unroll
  for (int w = 0; w < NH; ++w){
    float th = 0.5f * rxp[w];
    pc[w] = cosf(th);
    ps[w] = sinf(th);
  }

  // ---- hoisted lane/wave constants ----
  const int l5 = (lane>>5)&1, l4 = (lane>>4)&1, l3 = (lane>>3)&1;
  const int l2 = (lane>>2)&1, l1 = (lane>>1)&1, l0 = lane&1;
  const int pb2 = l4^l3, pb3 = l3^l2, pb4 = l2^l1, pb5 = l1^l0;
  const int a0 = l5, a1 = l5^l4;
  const int a6w = l0 ^ half;                       // beta6
  const int n_base = pb2 + pb3 + pb4 + pb5 + a6w;

  // phase constants (-i)^k per reg (step-invariant), 8 regs
  float cre8[NREG], cim8[NREG];
  #pragma unroll
  for (int r = 0; r < NREG; ++r){
    const int R0 = r&1, R1 = (r>>1)&1, R2 = (r>>2)&1;
    int k = (n_base + (a0^R0) + (a1^R0) + (half^R2) + (R2^R1) + (R1^R0)) & 3;
    cre8[r] = (k==0) ? 1.f : (k==2) ? -1.f : 0.f;
    cim8[r] = (k==1) ? -1.f : (k==3) ? 1.f : 0.f;
  }

  // measurement lane signs
  const float ls0 = (__popc(lane & 0x1F) & 1) ? -1.f : 1.f;
  const float ls1 = (__popc(lane & 0x30) & 1) ? -1.f : 1.f;
  const float ls2 = (__popc(lane & 0x38) & 1) ? -1.f : 1.f;
  const float ls3 = (__popc(lane & 0x3C) & 1) ? -1.f : 1.f;
  const float ls4 = (__popc(lane & 0x3E) & 1) ? -1.f : 1.f;
  const float ls5 = (__popc(lane & 0x3F) & 1) ? -1.f : 1.f;
  // wave-sign at combine: sigma = -1 for hidden units {0, 6..9}
  const float sig = (lane == 0 || lane >= 6) ? -1.f : 1.f;

  float h = 0.f, c = 0.f;   // lane j holds h_j, c_j redundantly in every wave

  const float* x0 = inp + (size_t)b * DDIM;
  float xa = x0[lane];
  float xb = x0[64 + lane];

  __syncthreads();

  #pragma unroll 1
  for (int t = 0; t < T_STEPS; ++t){
    float xaC = xa, xbC = xb;
    if (t + 1 < T_STEPS){
      const float* nx = inp + ((size_t)(t+1) * BATCH + b) * DDIM;
      xa = nx[lane];
      xb = nx[64 + lane];
    }

    // ---- gate pre-activation half-angles (both halves compute identically) ----
    float cs[NH], sn[NH];
    #pragma unroll
    for (int w = 0; w < NH; ++w){
      float p  = fmaf(xaC, wA[w], fmaf(xbC, wB[w], h * wC[w]));
      float th = 0.5f * (bT[w] + wave_sum_b(p));
      cs[w] = __cosf(th);
      sn[w] = __sinf(th);
    }

    // ---- build half-statevector: u[j] = prod-state(x+p) at K j ----
    float f2 = pb2 ? sn[2] : cs[2];
    float f3 = pb3 ? sn[3] : cs[3];
    float f4 = pb4 ? sn[4] : cs[4];
    float f5 = pb5 ? sn[5] : cs[5];
    float m2345 = ((f2*f3)*(f4*f5)) * (a6w ? sn[6] : cs[6]);  // wire-6 factor folded

    float q0 = (a0 ? sn[0] : cs[0]) * (a1 ? sn[1] : cs[1]);
    float q1 = (a0 ? cs[0] : sn[0]) * (a1 ? cs[1] : sn[1]);
    float Z0 = m2345 * q0, Z1 = m2345 * q1;

    float u7  = half ? sn[7] : cs[7];
    float u7b = half ? cs[7] : sn[7];
    float t78[4];
    t78[0] = u7  * cs[8];   // R2=0,R1=0
    t78[1] = u7  * sn[8];   // R2=0,R1=1
    t78[2] = u7b * sn[8];   // R2=1,R1=0
    t78[3] = u7b * cs[8];   // R2=1,R1=1

    float re[NREG], im[NREG];
    #pragma unroll
    for (int r = 0; r < NREG; ++r){
      const int b9 = ((r >> 1) ^ r) & 1;          // R1^R0
      float A = t78[r >> 1] * (b9 ? sn[9] : cs[9]);
      float m = A * ((r & 1) ? Z1 : Z0);
      re[r] = m * cre8[r];
      im[r] = m * cim8[r];
    }

    // ---- RX(p): lane wires 0..5, reg wires 7..9, then cross-wave wire 6 ----
    rx_lane(pc[0], ps[0], 32, re, im);
    rx_lane(pc[1], ps[1], 16, re, im);
    RX_LANE_DPP(lane_xor8, pc[2], ps[2])
    RX_LANE_DPP(lane_xor4, pc[3], ps[3])
    RX_LANE_DPP(qp2,       pc[4], ps[4])
    RX_LANE_DPP(qp1,       pc[5], ps[5])
    rx_reg<2>(pc[7], ps[7], re, im);
    rx_reg<1>(pc[8], ps[8], re, im);
    rx_reg<0>(pc[9], ps[9], re, im);

    // wire 6 (wave bit): exchange full half-state with partner wave via LDS
    Sx[g][half][0][lane] = make_float4(re[0], re[1], re[2], re[3]);
    Sx[g][half][1][lane] = make_float4(re[4], re[5], re[6], re[7]);
    Sx[g][half][2][lane] = make_float4(im[0], im[1], im[2], im[3]);
    Sx[g][half][3][lane] = make_float4(im[4], im[5], im[6], im[7]);
    __syncthreads();
    {
      float4 pr0 = Sx[g][half^1][0][lane];
      float4 pr1 = Sx[g][half^1][1][lane];
      float4 pi0 = Sx[g][half^1][2][lane];
      float4 pi1 = Sx[g][half^1][3][lane];
      float pre[NREG] = {pr0.x,pr0.y,pr0.z,pr0.w, pr1.x,pr1.y,pr1.z,pr1.w};
      float pim[NREG] = {pi0.x,pi0.y,pi0.z,pi0.w, pi1.x,pi1.y,pi1.z,pi1.w};
      const float c6 = pc[6], s6 = ps[6];
      #pragma unroll
      for (int r = 0; r < NREG; ++r){
        re[r] = fmaf(c6, re[r],  s6 * pim[r]);
        im[r] = fmaf(c6, im[r], -s6 * pre[r]);
      }
    }

    // ---- PauliZ partials (this wave's 512 amps); totals land in lane 63 ----
    float tot = 0.f, q4 = 0.f, q6 = 0.f, q7 = 0.f;
    #pragma unroll
    for (int r = 0; r < NREG; ++r){
      float p = fmaf(re[r], re[r], im[r]*im[r]);
      tot += p;
      q4 += ((__popc(r & 0x4) & 1) ? -p : p);
      q6 += ((__popc(r & 0x6) & 1) ? -p : p);
      q7 += ((__popc(r & 0x7) & 1) ? -p : p);
    }
    float P0 = red63(ls0 * q7);
    float P1 = red63(ls1 * tot);
    float P2 = red63(ls2 * tot);
    float P3 = red63(ls3 * tot);
    float P4 = red63(ls4 * tot);
    float P5 = red63(ls5 * tot);   // serves S5 (sigma +) and S6 (sigma -)
    float P7 = red63(ls5 * q4);
    float P8 = red63(ls5 * q6);
    float P9 = red63(ls5 * q7);
    if (lane == 63){
      float* pp = &part[g][half][0];
      pp[0] = P0; pp[1] = P1; pp[2] = P2; pp[3] = P3; pp[4] = P4;
      pp[5] = P5; pp[6] = P5; pp[7] = P7; pp[8] = P8; pp[9] = P9;
    }
    __syncthreads();

    // ---- combine partials + activations + cell (every lane, every wave) ----
    float E0 = part[0][0][lane] + sig * part[0][1][lane];
    float E1 = part[1][0][lane] + sig * part[1][1][lane];
    float E2 = part[2][0][lane] + sig * part[2][1][lane];
    float E3 = part[3][0][lane] + sig * part[3][1][lane];
    float fv = 1.f / (1.f + __expf(-E0));
    float iv = 1.f / (1.f + __expf(-E1));
    float e2g = __expf(2.f * E2);
    float gv = (e2g - 1.f) / (e2g + 1.f);
    float ov = 1.f / (1.f + __expf(-E3));
    c = fmaf(fv, c, iv * gv);
    float e2c = __expf(2.f * c);
    h = ov * ((e2c - 1.f) / (e2c + 1.f));

    if (wv == 0 && lane < NH)
      out[((size_t)t * BATCH + b) * NH + lane] = h;
  }

  // hT, cT
  if (wv == 0 && lane < NH){
    const size_t ysN = (size_t)T_STEPS * BATCH * NH;
    out[ysN + (size_t)b * NH + lane]                      = h;
    out[ysN + (size_t)BATCH * NH + (size_t)b * NH + lane] = c;
  }
}

extern "C" void kernel_launch(void* const* d_in, const int* in_sizes, int n_in,
                              void* d_out, int out_size, void* d_ws, size_t ws_size,
                              hipStream_t stream)
{
  qlstm_kernel<<<BATCH, 512, 0, stream>>>(
      (const float*)d_in[0], (const float*)d_in[1],
      (const float*)d_in[2], (const float*)d_in[3],
      (const float*)d_in[4], (const float*)d_in[5],
      (const float*)d_in[6], (const float*)d_in[7],
      (const float*)d_in[8], (const float*)d_in[9],
      (float*)d_out);
}